// Round 1
// baseline (254.291 us; speedup 1.0000x reference)
//
#include <hip/hip_runtime.h>
#include <hip/hip_bf16.h>
#include <stdint.h>

typedef __hip_bfloat16 bf16;
typedef __attribute__((ext_vector_type(8))) short short8;   // 8 bf16
typedef __attribute__((ext_vector_type(4))) float f32x4;

#define QSCALE 0.18033688011f   // 0.125 * log2(e), folded into Q at gemm0

// ---- 1-instr helpers ----
__device__ __forceinline__ float fast_exp2(float x) {
#if __has_builtin(__builtin_amdgcn_exp2f)
  return __builtin_amdgcn_exp2f(x);
#else
  return exp2f(x);
#endif
}

__device__ __forceinline__ uint32_t pack2_bf16(float a, float b) {
#if __has_builtin(__builtin_amdgcn_cvt_pk_bf16_f32)
  typedef __attribute__((ext_vector_type(2))) __bf16 bf16x2;
  bf16x2 v = __builtin_amdgcn_cvt_pk_bf16_f32(a, b);
  return __builtin_bit_cast(uint32_t, v);
#else
  uint32_t ua = __builtin_bit_cast(uint32_t, a);
  uint32_t ub = __builtin_bit_cast(uint32_t, b);
  ua += 0x7FFF + ((ua >> 16) & 1);   // RNE
  ub += 0x7FFF + ((ub >> 16) & 1);
  return (ua >> 16) | (ub & 0xFFFF0000u);
#endif
}

// async global->LDS, 16B per lane, LDS dest = wave-uniform base + lane*16
__device__ __forceinline__ void gload_lds16(const bf16* g, bf16* l) {
#if __has_builtin(__builtin_amdgcn_global_load_lds)
  __builtin_amdgcn_global_load_lds(
      (const __attribute__((address_space(1))) void*)(uintptr_t)g,
      (__attribute__((address_space(3))) void*)(uint32_t)(uintptr_t)l,
      16, 0, 0);
#else
  int lane = threadIdx.x & 63;
  *(short8*)(l + lane * 8) = *(const short8*)(g + lane * 8);
#endif
}

// ---- fp32->bf16 transpose tile body (64x64) ----
__device__ __forceinline__ void transpose_tile(const float* __restrict__ in,
                                               bf16* __restrict__ out,
                                               int R, int C, int bx, int by,
                                               bf16 (*t)[72]) {
  const int r0 = by * 64, c0 = bx * 64;
  const int rr = threadIdx.x >> 3, cc = (threadIdx.x & 7) * 8;
#pragma unroll
  for (int rep = 0; rep < 2; ++rep) {
    int y = rr + rep * 32;
    const float* p = in + (size_t)(r0 + y) * C + c0 + cc;
    f32x4 v0 = *(const f32x4*)p;
    f32x4 v1 = *(const f32x4*)(p + 4);
#pragma unroll
    for (int j = 0; j < 4; ++j) {
      t[cc + j][y] = __float2bfloat16(v0[j]);
      t[cc + 4 + j][y] = __float2bfloat16(v1[j]);
    }
  }
  __syncthreads();
#pragma unroll
  for (int rep = 0; rep < 2; ++rep) {
    int y = rr + rep * 32;
    short8 v = *(const short8*)&t[y][cc];
    *(short8*)(out + (size_t)(c0 + y) * R + r0 + cc) = v;
  }
}

// ---- fused prep: x->bf16 (blocks 0..2047), Wqkv^T (2048..2815),
//      Wproj^T (2816..3071) ----
__global__ __launch_bounds__(256)
void prep_k(const float* __restrict__ x, bf16* __restrict__ xb,
            const float* __restrict__ Wqkv, bf16* __restrict__ WtQkv,
            const float* __restrict__ Wproj, bf16* __restrict__ WtP) {
  __shared__ __align__(16) bf16 t[64][72];
  const int bid = blockIdx.x;
  if (bid < 2048) {
    int i = (bid * 256 + threadIdx.x) * 8;
    f32x4 v0 = *(const f32x4*)(x + i);
    f32x4 v1 = *(const f32x4*)(x + i + 4);
    short8 r;
    bf16* rb = (bf16*)&r;
#pragma unroll
    for (int j = 0; j < 4; ++j) {
      rb[j] = __float2bfloat16(v0[j]);
      rb[4 + j] = __float2bfloat16(v1[j]);
    }
    *(short8*)(xb + i) = r;
  } else if (bid < 2048 + 768) {
    int b = bid - 2048;
    transpose_tile(Wqkv, WtQkv, 1024, 3072, b % 48, b / 48, t);
  } else {
    int b = bid - 2816;
    transpose_tile(Wproj, WtP, 1024, 1024, b % 16, b / 16, t);
  }
}

// ---------------- GEMM: C[m][n] = A[m,:]·Bt[n,:] + bias[n] -------------------
// MODE 0 (TM=128): LDS-transposed coalesced epilogue -> Q (xQSCALE) / K as
//                  [bh][t][64], V^T as [bh][64][t]. All 16B/lane stores.
// MODE 1 (TM=64):  fp32 out row-major [M,Nn].
template <int MODE, int TM>
__global__ __launch_bounds__(256, 2)
void gemm_bt(const bf16* __restrict__ A, const bf16* __restrict__ Bt,
             const float* __restrict__ bias, float* __restrict__ outp,
             bf16* __restrict__ Qd, bf16* __restrict__ Kd, bf16* __restrict__ Vt,
             int M, int Nn, int K) {
  constexpr int MI = TM / 32;
  // staging (TM*32 + 4096 el) and MODE-0 epilogue (<=9216 el) share this pool
  __shared__ __align__(16) bf16 smem[(TM == 128) ? 9216 : 6144];
  bf16* As = smem;
  bf16* Bs = smem + TM * 32;

  const int tid = threadIdx.x;
  const int wave = tid >> 6, lane = tid & 63;
  const int quad = lane >> 4, l16 = lane & 15;
  const int mw = (wave >> 1) * (TM / 2), nw = (wave & 1) * 64;
  const int m_blk = blockIdx.y * TM, n_blk = blockIdx.x * 128;

  f32x4 acc[MI][4];
#pragma unroll
  for (int i = 0; i < MI; ++i)
#pragma unroll
    for (int j = 0; j < 4; ++j) acc[i][j] = (f32x4){0.f, 0.f, 0.f, 0.f};

  const int rowA = lane >> 2, colA = (lane & 3) * 8;
  const int chunkB = wave * 2;
  const bf16* gB = Bt + (size_t)(n_blk + chunkB * 16 + rowA) * K + colA;
  bf16* lB0 = &Bs[chunkB * 16 * 32];
  bf16* lB1 = &Bs[(chunkB + 1) * 16 * 32];

  const int chunkA = (TM == 128) ? wave * 2 : wave;
  const bf16* gA = A + (size_t)(m_blk + chunkA * 16 + rowA) * K + colA;
  bf16* lA0 = &As[chunkA * 16 * 32];
  bf16* lA1 = &As[(chunkA + 1) * 16 * 32];  // unused for TM=64

  for (int kt = 0; kt < K; kt += 32) {
    gload_lds16(gA, lA0);
    if (TM == 128) gload_lds16(gA + 16 * K, lA1);
    gload_lds16(gB, lB0);
    gload_lds16(gB + 16 * K, lB1);
    gA += 32; gB += 32;
    __syncthreads();
    short8 af[MI], bfv[4];
#pragma unroll
    for (int i = 0; i < MI; ++i)
      af[i] = *(const short8*)&As[(mw + i * 16 + l16) * 32 + quad * 8];
#pragma unroll
    for (int j = 0; j < 4; ++j)
      bfv[j] = *(const short8*)&Bs[(nw + j * 16 + l16) * 32 + quad * 8];
#pragma unroll
    for (int i = 0; i < MI; ++i)
#pragma unroll
      for (int j = 0; j < 4; ++j)
        acc[i][j] = __builtin_amdgcn_mfma_f32_16x16x32_bf16(af[i], bfv[j],
                                                            acc[i][j], 0, 0, 0);
    __syncthreads();
  }

  if (MODE == 0) {
    // per-j bias for this wave's columns
    float bval[4];
#pragma unroll
    for (int j = 0; j < 4; ++j) bval[j] = bias[n_blk + nw + j * 16 + l16];

    const int part = n_blk >> 10;          // 0:q 1:k 2:v (block-uniform)
    const int b = m_blk >> 11;
    const int tloc = m_blk & 2047;
    const int h0 = (n_blk & 1023) >> 6;

#pragma unroll
    for (int p = 0; p < 2; ++p) {          // feature halves (64 cols = 1 head)
      __syncthreads();
      if ((nw >> 6) == p) {
        if (part == 2) {
          // V half-tile as [64 d][136 t], 8B-packed writes (r -> t contiguous)
#pragma unroll
          for (int i = 0; i < MI; ++i)
#pragma unroll
            for (int j = 0; j < 4; ++j) {
              const int dh = j * 16 + l16;
              const int t0 = mw + i * 16 + quad * 4;
              uint2 pk;
              pk.x = pack2_bf16(acc[i][j][0] + bval[j], acc[i][j][1] + bval[j]);
              pk.y = pack2_bf16(acc[i][j][2] + bval[j], acc[i][j][3] + bval[j]);
              *(uint2*)&smem[dh * 136 + t0] = pk;
            }
        } else {
          // Q/K half-tile as [128 t][72 d] (stride-72: conflict-free writes)
          const float sc = (part == 0) ? QSCALE : 1.0f;
#pragma unroll
          for (int i = 0; i < MI; ++i)
#pragma unroll
            for (int j = 0; j < 4; ++j) {
              const int d = j * 16 + l16;
              const int t0 = mw + i * 16 + quad * 4;
#pragma unroll
              for (int r = 0; r < 4; ++r)
                smem[(t0 + r) * 72 + d] =
                    __float2bfloat16((acc[i][j][r] + bval[j]) * sc);
            }
        }
      }
      __syncthreads();
      const size_t bh = (size_t)(b * 16 + h0 + p);
      if (part == 2) {
#pragma unroll
        for (int it = 0; it < 4; ++it) {
          const int dl = (tid >> 4) + it * 16;
          const int t8 = (tid & 15) * 8;
          short8 v = *(const short8*)&smem[dl * 136 + t8];
          *(short8*)&Vt[(bh * 64 + dl) * 2048 + tloc + t8] = v;
        }
      } else {
        bf16* dst = (part == 0) ? Qd : Kd;
#pragma unroll
        for (int it = 0; it < 4; ++it) {
          const int row = (tid >> 3) + it * 32;
          const int col8 = (tid & 7) * 8;
          short8 v = *(const short8*)&smem[row * 72 + col8];
          *(short8*)&dst[(bh * 2048 + tloc + row) * 64 + col8] = v;
        }
      }
    }
  } else {
#pragma unroll
    for (int j = 0; j < 4; ++j) {
      const int ncol = n_blk + nw + j * 16 + l16;
      const float bval = bias[ncol];
#pragma unroll
      for (int i = 0; i < MI; ++i) {
        const int mrow0 = m_blk + mw + i * 16 + quad * 4;
#pragma unroll
        for (int r = 0; r < 4; ++r)
          outp[(size_t)(mrow0 + r) * Nn + ncol] = acc[i][j][r] + bval;
      }
    }
  }
}

// ---------------- flash attention: Qtile=64, KVtile=64, quadrant split -------
// Wave (qh,kvh) owns q-half x kv-half. S^T = K·Q^T: C col=l16=q, row=kv.
// Q pre-scaled; deferred normalization.
//
// BARRIER-FREE main loop: K and V^T fragments are loaded DIRECTLY from global
// (L1/L2-resident: K+V per head = 512 KB) in MFMA fragment layout, single-
// buffered in registers with one-tile-ahead prefetch. The P round-trip through
// LDS is a WITHIN-WAVE transpose (wave writes and reads only its own 32x32
// quadrant; quadrants are byte-disjoint across waves) -> no inter-wave hazard,
// so the loop needs no __syncthreads at all. LDS traffic drops 64KB -> 16KB
// per block-iteration and all 4 waves run latency-decoupled.
__global__ __launch_bounds__(256, 4)
void attn_kernel(const bf16* __restrict__ Qg, const bf16* __restrict__ Kg,
                 const bf16* __restrict__ Vt, bf16* __restrict__ yg) {
  // Ps [64][72] bf16 (9216 B) unioned with the epilogue reduction scratch
  // (16384 B Y-partials + 256 B sums). 16640 B total.
  __shared__ __align__(16) char lds_pool[16640];
  bf16 (*Ps)[72] = (bf16 (*)[72])lds_pool;

  const int tid = threadIdx.x;
  const int wave = tid >> 6, lane = tid & 63;
  const int quad = lane >> 4, l16 = lane & 15;
  const int qh = wave & 1, kvh = wave >> 1;

  const int bx = blockIdx.x;
  const int qt = bx & 31;                // 32 q-tiles of 64
  const int bh = bx >> 5;                // b*16 + h

  const bf16* Qb = Qg + ((size_t)bh * 2048 + qt * 64) * 64;
  // per-lane fragment streams:
  //  kf[kvblk][ks] = K[kvh*32 + kvblk*16 + l16][ks*32 + quad*8 ..+8]
  //  vf[dblk]      = V^T[dblk*16 + l16][kt + kvh*32 + quad*8 ..+8]
  const bf16* kp = Kg + ((size_t)bh * 2048 + kvh * 32 + l16) * 64 + quad * 8;
  const bf16* vp = Vt + ((size_t)bh * 64 + l16) * 2048 + kvh * 32 + quad * 8;

  short8 qf[2][2];
#pragma unroll
  for (int qblk = 0; qblk < 2; ++qblk)
#pragma unroll
    for (int kb = 0; kb < 2; ++kb)
      qf[qblk][kb] = *(const short8*)(
          Qb + (size_t)(qh * 32 + qblk * 16 + l16) * 64 + kb * 32 + quad * 8);

  // tile 0 fragments
  short8 kf[2][2], vf[4];
#pragma unroll
  for (int kvblk = 0; kvblk < 2; ++kvblk)
#pragma unroll
    for (int ks = 0; ks < 2; ++ks)
      kf[kvblk][ks] = *(const short8*)(kp + kvblk * 1024 + ks * 32);
#pragma unroll
  for (int dblk = 0; dblk < 4; ++dblk)
    vf[dblk] = *(const short8*)(vp + (size_t)dblk * 16 * 2048);

  f32x4 yacc[2][4];
#pragma unroll
  for (int qblk = 0; qblk < 2; ++qblk)
#pragma unroll
    for (int dblk = 0; dblk < 4; ++dblk)
      yacc[qblk][dblk] = (f32x4){0.f, 0.f, 0.f, 0.f};
  float sum_l[2] = {0.f, 0.f};

  for (int kt = 0; kt < 2048; kt += 64) {
    // 1. S^T quadrant from current K fragments
    f32x4 st[2][2];
#pragma unroll
    for (int kvblk = 0; kvblk < 2; ++kvblk)
#pragma unroll
      for (int qblk = 0; qblk < 2; ++qblk) {
        f32x4 a = (f32x4){0.f, 0.f, 0.f, 0.f};
        a = __builtin_amdgcn_mfma_f32_16x16x32_bf16(kf[kvblk][0], qf[qblk][0],
                                                    a, 0, 0, 0);
        a = __builtin_amdgcn_mfma_f32_16x16x32_bf16(kf[kvblk][1], qf[qblk][1],
                                                    a, 0, 0, 0);
        st[qblk][kvblk] = a;
      }

    // 2. prefetch next K tile into the same regs (WAR is safe: in-order issue)
    if (kt + 64 < 2048) {
      kp += 64 * 64;
#pragma unroll
      for (int kvblk = 0; kvblk < 2; ++kvblk)
#pragma unroll
        for (int ks = 0; ks < 2; ++ks)
          kf[kvblk][ks] = *(const short8*)(kp + kvblk * 1024 + ks * 32);
    }

    // 3. deferred softmax -> own Ps quadrant (within-wave, no barrier)
#pragma unroll
    for (int qblk = 0; qblk < 2; ++qblk) {
      float ssum = 0.f;
#pragma unroll
      for (int kvblk = 0; kvblk < 2; ++kvblk) {
        float p0 = fast_exp2(st[qblk][kvblk][0]);
        float p1 = fast_exp2(st[qblk][kvblk][1]);
        float p2 = fast_exp2(st[qblk][kvblk][2]);
        float p3 = fast_exp2(st[qblk][kvblk][3]);
        ssum += (p0 + p1) + (p2 + p3);
        uint2 pk;
        pk.x = pack2_bf16(p0, p1);
        pk.y = pack2_bf16(p2, p3);
        *(uint2*)&Ps[qh * 32 + qblk * 16 + l16]
                    [kvh * 32 + kvblk * 16 + quad * 4] = pk;
      }
      sum_l[qblk] += ssum;
    }

    // 4. Y += P V over this wave's kv-half (pa read-after-write is same-wave;
    //    compiler inserts the lgkmcnt)
#pragma unroll
    for (int qblk = 0; qblk < 2; ++qblk) {
      short8 pa = *(const short8*)&Ps[qh * 32 + qblk * 16 + l16]
                                     [kvh * 32 + quad * 8];
#pragma unroll
      for (int dblk = 0; dblk < 4; ++dblk)
        yacc[qblk][dblk] = __builtin_amdgcn_mfma_f32_16x16x32_bf16(
            pa, vf[dblk], yacc[qblk][dblk], 0, 0, 0);
    }

    // 5. prefetch next V tile
    if (kt + 64 < 2048) {
      vp += 64;
#pragma unroll
      for (int dblk = 0; dblk < 4; ++dblk)
        vf[dblk] = *(const short8*)(vp + (size_t)dblk * 16 * 2048);
    }
  }

  // ---- reductions: quads within wave, then kv-halves across waves ----
#pragma unroll
  for (int qblk = 0; qblk < 2; ++qblk) {
    sum_l[qblk] += __shfl_xor(sum_l[qblk], 16);
    sum_l[qblk] += __shfl_xor(sum_l[qblk], 32);
  }
  __syncthreads();   // all waves done with Ps before scratch overwrites it
  float* red = (float*)lds_pool;               // 16384 B Y-partials
  float* sred = (float*)(lds_pool + 16384);    // 256 B sums
  if (kvh == 1) {
#pragma unroll
    for (int qblk = 0; qblk < 2; ++qblk) {
#pragma unroll
      for (int dblk = 0; dblk < 4; ++dblk) {
        const int f = (qh * 2 + qblk) * 4 + dblk;
        *(f32x4*)&red[(f * 64 + quad * 16 + l16) * 4] = yacc[qblk][dblk];
      }
      if (quad == 0) sred[(qh * 2 + qblk) * 16 + l16] = sum_l[qblk];
    }
  }
  __syncthreads();
  if (kvh == 0) {
    const int b = bh >> 4, h = bh & 15;
    const size_t rowbase = (size_t)b * 2048 + qt * 64;
#pragma unroll
    for (int qblk = 0; qblk < 2; ++qblk) {
      sum_l[qblk] += sred[(qh * 2 + qblk) * 16 + l16];
#pragma unroll
      for (int dblk = 0; dblk < 4; ++dblk) {
        const int f = (qh * 2 + qblk) * 4 + dblk;
        f32x4 o = *(const f32x4*)&red[(f * 64 + quad * 16 + l16) * 4];
#pragma unroll
        for (int r = 0; r < 4; ++r) yacc[qblk][dblk][r] += o[r];
      }
#pragma unroll
      for (int r = 0; r < 4; ++r) {
        const float lv = __shfl(sum_l[qblk], quad * 4 + r, 16);
        const float inv = 1.f / lv;
        const int rr = qh * 32 + qblk * 16 + quad * 4 + r;
#pragma unroll
        for (int dblk = 0; dblk < 4; ++dblk)
          yg[(rowbase + rr) * 1024 + h * 64 + dblk * 16 + l16] =
              __float2bfloat16(yacc[qblk][dblk][r] * inv);
      }
    }
  }
}

// ---------------- launch ----------------
extern "C" void kernel_launch(void* const* d_in, const int* in_sizes, int n_in,
                              void* d_out, int out_size, void* d_ws, size_t ws_size,
                              hipStream_t stream) {
  const float* x = (const float*)d_in[0];      // [4096, 1024] fp32
  const float* Wqkv = (const float*)d_in[1];   // [1024, 3072] fp32
  const float* bqkv = (const float*)d_in[2];   // [3072] fp32
  const float* Wproj = (const float*)d_in[3];  // [1024, 1024] fp32
  const float* bproj = (const float*)d_in[4];  // [1024] fp32
  float* out = (float*)d_out;                  // [4096, 1024] fp32

  if (ws_size < (size_t)40 * 1024 * 1024) return;

  char* ws = (char*)d_ws;
  bf16* xb    = (bf16*)(ws + 0);             // [4096,1024] = 8 MiB
  bf16* yd    = (bf16*)(ws + 0);             // aliases xb (dead after gemm0)
  bf16* WtQkv = (bf16*)(ws + 8388608);       // [3072,1024] = 6 MiB
  bf16* WtP   = (bf16*)(ws + 14680064);      // [1024,1024] = 2 MiB
  bf16* Qd    = (bf16*)(ws + 16777216);      // [32,2048,64] = 8 MiB (pre-scaled)
  bf16* Kd    = (bf16*)(ws + 25165824);      // 8 MiB
  bf16* Vten  = (bf16*)(ws + 33554432);      // [32,64,2048] = 8 MiB

  prep_k<<<3072, 256, 0, stream>>>(x, xb, Wqkv, WtQkv, Wproj, WtP);
  gemm_bt<0, 128><<<dim3(24, 32), 256, 0, stream>>>(
      xb, WtQkv, bqkv, nullptr, Qd, Kd, Vten, 4096, 3072, 1024);
  attn_kernel<<<dim3(1024), 256, 0, stream>>>(Qd, Kd, Vten, yd);
  gemm_bt<1, 64><<<dim3(8, 64), 256, 0, stream>>>(
      yd, WtP, bproj, out, nullptr, nullptr, nullptr, 4096, 1024, 1024);
}

// Round 2
// 202.144 us; speedup vs baseline: 1.2580x; 1.2580x over previous
//
#include <hip/hip_runtime.h>
#include <hip/hip_bf16.h>
#include <stdint.h>

typedef __hip_bfloat16 bf16;
typedef __attribute__((ext_vector_type(8))) short short8;   // 8 bf16
typedef __attribute__((ext_vector_type(4))) short s16x4;    // 4 bf16
typedef __attribute__((ext_vector_type(4))) float f32x4;

#define QSCALE 0.18033688011f   // 0.125 * log2(e), folded into Q at gemm0

// ---- 1-instr helpers ----
__device__ __forceinline__ float fast_exp2(float x) {
#if __has_builtin(__builtin_amdgcn_exp2f)
  return __builtin_amdgcn_exp2f(x);
#else
  return exp2f(x);
#endif
}

__device__ __forceinline__ uint32_t pack2_bf16(float a, float b) {
#if __has_builtin(__builtin_amdgcn_cvt_pk_bf16_f32)
  typedef __attribute__((ext_vector_type(2))) __bf16 bf16x2;
  bf16x2 v = __builtin_amdgcn_cvt_pk_bf16_f32(a, b);
  return __builtin_bit_cast(uint32_t, v);
#else
  uint32_t ua = __builtin_bit_cast(uint32_t, a);
  uint32_t ub = __builtin_bit_cast(uint32_t, b);
  ua += 0x7FFF + ((ua >> 16) & 1);   // RNE
  ub += 0x7FFF + ((ub >> 16) & 1);
  return (ua >> 16) | (ub & 0xFFFF0000u);
#endif
}

// 16x16x16 bf16 MFMA (K=16): A/B = 4 bf16 (2 VGPR), C/D = f32x4
#if __has_builtin(__builtin_amdgcn_mfma_f32_16x16x16bf16_1k)
#define MFMA_PV(a, b, c) __builtin_amdgcn_mfma_f32_16x16x16bf16_1k(a, b, c, 0, 0, 0)
#elif __has_builtin(__builtin_amdgcn_mfma_f32_16x16x16_bf16_1k)
#define MFMA_PV(a, b, c) __builtin_amdgcn_mfma_f32_16x16x16_bf16_1k(a, b, c, 0, 0, 0)
#else
__device__ __forceinline__ f32x4 mfma_pv_asm(s16x4 a, s16x4 b, f32x4 c) {
  f32x4 d;
  asm("v_mfma_f32_16x16x16_bf16 %0, %1, %2, %3"
      : "=&v"(d) : "v"(a), "v"(b), "v"(c));
  return d;
}
#define MFMA_PV(a, b, c) mfma_pv_asm(a, b, c)
#endif

// async global->LDS, 16B per lane, LDS dest = wave-uniform base + lane*16
__device__ __forceinline__ void gload_lds16(const bf16* g, bf16* l) {
#if __has_builtin(__builtin_amdgcn_global_load_lds)
  __builtin_amdgcn_global_load_lds(
      (const __attribute__((address_space(1))) void*)(uintptr_t)g,
      (__attribute__((address_space(3))) void*)(uint32_t)(uintptr_t)l,
      16, 0, 0);
#else
  int lane = threadIdx.x & 63;
  *(short8*)(l + lane * 8) = *(const short8*)(g + lane * 8);
#endif
}

// LDS-only barrier (no vmcnt drain): keeps global prefetch loads in flight.
__device__ __forceinline__ void lds_barrier() {
  asm volatile("s_waitcnt lgkmcnt(0)\n\ts_barrier" ::: "memory");
}

// ---- fp32->bf16 transpose tile body (64x64) ----
__device__ __forceinline__ void transpose_tile(const float* __restrict__ in,
                                               bf16* __restrict__ out,
                                               int R, int C, int bx, int by,
                                               bf16 (*t)[72]) {
  const int r0 = by * 64, c0 = bx * 64;
  const int rr = threadIdx.x >> 3, cc = (threadIdx.x & 7) * 8;
#pragma unroll
  for (int rep = 0; rep < 2; ++rep) {
    int y = rr + rep * 32;
    const float* p = in + (size_t)(r0 + y) * C + c0 + cc;
    f32x4 v0 = *(const f32x4*)p;
    f32x4 v1 = *(const f32x4*)(p + 4);
#pragma unroll
    for (int j = 0; j < 4; ++j) {
      t[cc + j][y] = __float2bfloat16(v0[j]);
      t[cc + 4 + j][y] = __float2bfloat16(v1[j]);
    }
  }
  __syncthreads();
#pragma unroll
  for (int rep = 0; rep < 2; ++rep) {
    int y = rr + rep * 32;
    short8 v = *(const short8*)&t[y][cc];
    *(short8*)(out + (size_t)(c0 + y) * R + r0 + cc) = v;
  }
}

// ---- fused prep: x->bf16 (blocks 0..2047), Wqkv^T (2048..2815),
//      Wproj^T (2816..3071) ----
__global__ __launch_bounds__(256)
void prep_k(const float* __restrict__ x, bf16* __restrict__ xb,
            const float* __restrict__ Wqkv, bf16* __restrict__ WtQkv,
            const float* __restrict__ Wproj, bf16* __restrict__ WtP) {
  __shared__ __align__(16) bf16 t[64][72];
  const int bid = blockIdx.x;
  if (bid < 2048) {
    int i = (bid * 256 + threadIdx.x) * 8;
    f32x4 v0 = *(const f32x4*)(x + i);
    f32x4 v1 = *(const f32x4*)(x + i + 4);
    short8 r;
    bf16* rb = (bf16*)&r;
#pragma unroll
    for (int j = 0; j < 4; ++j) {
      rb[j] = __float2bfloat16(v0[j]);
      rb[4 + j] = __float2bfloat16(v1[j]);
    }
    *(short8*)(xb + i) = r;
  } else if (bid < 2048 + 768) {
    int b = bid - 2048;
    transpose_tile(Wqkv, WtQkv, 1024, 3072, b % 48, b / 48, t);
  } else {
    int b = bid - 2816;
    transpose_tile(Wproj, WtP, 1024, 1024, b % 16, b / 16, t);
  }
}

// ---------------- GEMM: C[m][n] = A[m,:]·Bt[n,:] + bias[n] -------------------
// MODE 0 (TM=128): LDS-transposed coalesced epilogue -> Q (xQSCALE) / K as
//                  [bh][t][64], V^T as [bh][64][t]. All 16B/lane stores.
// MODE 1 (TM=64):  fp32 out row-major [M,Nn].
template <int MODE, int TM>
__global__ __launch_bounds__(256, 2)
void gemm_bt(const bf16* __restrict__ A, const bf16* __restrict__ Bt,
             const float* __restrict__ bias, float* __restrict__ outp,
             bf16* __restrict__ Qd, bf16* __restrict__ Kd, bf16* __restrict__ Vt,
             int M, int Nn, int K) {
  constexpr int MI = TM / 32;
  // staging (TM*32 + 4096 el) and MODE-0 epilogue (<=9216 el) share this pool
  __shared__ __align__(16) bf16 smem[(TM == 128) ? 9216 : 6144];
  bf16* As = smem;
  bf16* Bs = smem + TM * 32;

  const int tid = threadIdx.x;
  const int wave = tid >> 6, lane = tid & 63;
  const int quad = lane >> 4, l16 = lane & 15;
  const int mw = (wave >> 1) * (TM / 2), nw = (wave & 1) * 64;
  const int m_blk = blockIdx.y * TM, n_blk = blockIdx.x * 128;

  f32x4 acc[MI][4];
#pragma unroll
  for (int i = 0; i < MI; ++i)
#pragma unroll
    for (int j = 0; j < 4; ++j) acc[i][j] = (f32x4){0.f, 0.f, 0.f, 0.f};

  const int rowA = lane >> 2, colA = (lane & 3) * 8;
  const int chunkB = wave * 2;
  const bf16* gB = Bt + (size_t)(n_blk + chunkB * 16 + rowA) * K + colA;
  bf16* lB0 = &Bs[chunkB * 16 * 32];
  bf16* lB1 = &Bs[(chunkB + 1) * 16 * 32];

  const int chunkA = (TM == 128) ? wave * 2 : wave;
  const bf16* gA = A + (size_t)(m_blk + chunkA * 16 + rowA) * K + colA;
  bf16* lA0 = &As[chunkA * 16 * 32];
  bf16* lA1 = &As[(chunkA + 1) * 16 * 32];  // unused for TM=64

  for (int kt = 0; kt < K; kt += 32) {
    gload_lds16(gA, lA0);
    if (TM == 128) gload_lds16(gA + 16 * K, lA1);
    gload_lds16(gB, lB0);
    gload_lds16(gB + 16 * K, lB1);
    gA += 32; gB += 32;
    __syncthreads();
    short8 af[MI], bfv[4];
#pragma unroll
    for (int i = 0; i < MI; ++i)
      af[i] = *(const short8*)&As[(mw + i * 16 + l16) * 32 + quad * 8];
#pragma unroll
    for (int j = 0; j < 4; ++j)
      bfv[j] = *(const short8*)&Bs[(nw + j * 16 + l16) * 32 + quad * 8];
#pragma unroll
    for (int i = 0; i < MI; ++i)
#pragma unroll
      for (int j = 0; j < 4; ++j)
        acc[i][j] = __builtin_amdgcn_mfma_f32_16x16x32_bf16(af[i], bfv[j],
                                                            acc[i][j], 0, 0, 0);
    __syncthreads();
  }

  if (MODE == 0) {
    // per-j bias for this wave's columns
    float bval[4];
#pragma unroll
    for (int j = 0; j < 4; ++j) bval[j] = bias[n_blk + nw + j * 16 + l16];

    const int part = n_blk >> 10;          // 0:q 1:k 2:v (block-uniform)
    const int b = m_blk >> 11;
    const int tloc = m_blk & 2047;
    const int h0 = (n_blk & 1023) >> 6;

#pragma unroll
    for (int p = 0; p < 2; ++p) {          // feature halves (64 cols = 1 head)
      __syncthreads();
      if ((nw >> 6) == p) {
        if (part == 2) {
          // V half-tile as [64 d][136 t], 8B-packed writes (r -> t contiguous)
#pragma unroll
          for (int i = 0; i < MI; ++i)
#pragma unroll
            for (int j = 0; j < 4; ++j) {
              const int dh = j * 16 + l16;
              const int t0 = mw + i * 16 + quad * 4;
              uint2 pk;
              pk.x = pack2_bf16(acc[i][j][0] + bval[j], acc[i][j][1] + bval[j]);
              pk.y = pack2_bf16(acc[i][j][2] + bval[j], acc[i][j][3] + bval[j]);
              *(uint2*)&smem[dh * 136 + t0] = pk;
            }
        } else {
          // Q/K half-tile as [128 t][72 d] (stride-72: conflict-free writes)
          const float sc = (part == 0) ? QSCALE : 1.0f;
#pragma unroll
          for (int i = 0; i < MI; ++i)
#pragma unroll
            for (int j = 0; j < 4; ++j) {
              const int d = j * 16 + l16;
              const int t0 = mw + i * 16 + quad * 4;
#pragma unroll
              for (int r = 0; r < 4; ++r)
                smem[(t0 + r) * 72 + d] =
                    __float2bfloat16((acc[i][j][r] + bval[j]) * sc);
            }
        }
      }
      __syncthreads();
      const size_t bh = (size_t)(b * 16 + h0 + p);
      if (part == 2) {
#pragma unroll
        for (int it = 0; it < 4; ++it) {
          const int dl = (tid >> 4) + it * 16;
          const int t8 = (tid & 15) * 8;
          short8 v = *(const short8*)&smem[dl * 136 + t8];
          *(short8*)&Vt[(bh * 64 + dl) * 2048 + tloc + t8] = v;
        }
      } else {
        bf16* dst = (part == 0) ? Qd : Kd;
#pragma unroll
        for (int it = 0; it < 4; ++it) {
          const int row = (tid >> 3) + it * 32;
          const int col8 = (tid & 7) * 8;
          short8 v = *(const short8*)&smem[row * 72 + col8];
          *(short8*)&dst[(bh * 2048 + tloc + row) * 64 + col8] = v;
        }
      }
    }
  } else {
#pragma unroll
    for (int j = 0; j < 4; ++j) {
      const int ncol = n_blk + nw + j * 16 + l16;
      const float bval = bias[ncol];
#pragma unroll
      for (int i = 0; i < MI; ++i) {
        const int mrow0 = m_blk + mw + i * 16 + quad * 4;
#pragma unroll
        for (int r = 0; r < 4; ++r)
          outp[(size_t)(mrow0 + r) * Nn + ncol] = acc[i][j][r] + bval;
      }
    }
  }
}

// ---------------- flash attention: Qtile=64, KVtile=64, kv-quarter waves -----
// Wave w owns kv rows [w*16, w*16+16) x ALL 64 q. S^T = K·Q^T per qblk:
// lane (quad,l16) holds S[q=qblk*16+l16][kv=quad*4+r] -- which is EXACTLY the
// A-fragment layout of mfma_f32_16x16x16_bf16 (k=quad*4+e). So P = exp2(S)
// stays in registers: no P LDS round-trip, no transpose. K/V LDS read
// amplification drops 2x -> 1x (wave reads only its 16 K rows; V as b64
// fragments). K AND V double-buffered in one 36864B pool -> ONE lds_barrier
// per iteration. Epilogue: 2-phase 4-way cross-wave reduction.
__global__ __launch_bounds__(256, 3)
void attn_kernel(const bf16* __restrict__ Qg, const bf16* __restrict__ Kg,
                 const bf16* __restrict__ Vt, bf16* __restrict__ yg) {
  // [0,18432): Ks[2][64][72]; [18432,36864): Vts[2][64*72].
  // Epilogue reuse: red = 2 x 16KB partials at 0; sred = 1KB at 32768.
  __shared__ __align__(16) char pool[36864];
  bf16* KsB = (bf16*)pool;
  bf16* VtsB = (bf16*)(pool + 18432);

  const int tid = threadIdx.x;
  const int wave = tid >> 6, lane = tid & 63;   // wave = kv quarter
  const int quad = lane >> 4, l16 = lane & 15;

  const int bx = blockIdx.x;
  const int qt = bx & 31;                // 32 q-tiles of 64
  const int bh = bx >> 5;                // b*16 + h

  const bf16* Qb = Qg + ((size_t)bh * 2048 + qt * 64) * 64;
  const bf16* Kb = Kg + (size_t)bh * 2048 * 64;
  const bf16* Vtb = Vt + (size_t)bh * 64 * 2048;

  // Q fragments for all 4 qblks (Q pre-scaled by QSCALE at gemm0)
  short8 qf[4][2];
#pragma unroll
  for (int qblk = 0; qblk < 4; ++qblk)
#pragma unroll
    for (int ks = 0; ks < 2; ++ks)
      qf[qblk][ks] = *(const short8*)(
          Qb + (size_t)(qblk * 16 + l16) * 64 + ks * 32 + quad * 8);

  // staging addressing (block-cooperative, coalesced global reads)
  const int kr = tid >> 3, kc = (tid & 7) * 8;
  const int vdd = tid & 63, vo = tid >> 6;
  const int voff0 = vdd * 72 + (((vo) + (vdd >> 3)) & 7) * 8;
  const int voff1 = vdd * 72 + (((vo + 4) + (vdd >> 3)) & 7) * 8;
  const bf16* Kp0 = Kb + (size_t)kr * 64 + kc;
  const bf16* Kp1 = Kb + (size_t)(kr + 32) * 64 + kc;
  const bf16* Vp0 = Vtb + (size_t)vdd * 2048 + vo * 8;
  const bf16* Vp1 = Vtb + (size_t)vdd * 2048 + (vo + 4) * 8;

  // preamble: tile0 -> buf0; tile1 -> regs
  {
    short8 a = *(const short8*)Kp0;
    short8 b = *(const short8*)Kp1;
    short8 c = *(const short8*)Vp0;
    short8 d = *(const short8*)Vp1;
    *(short8*)(KsB + kr * 72 + kc) = a;
    *(short8*)(KsB + (kr + 32) * 72 + kc) = b;
    *(short8*)(VtsB + voff0) = c;
    *(short8*)(VtsB + voff1) = d;
  }
  short8 gk0 = *(const short8*)(Kp0 + (size_t)64 * 64);
  short8 gk1 = *(const short8*)(Kp1 + (size_t)64 * 64);
  short8 gv0 = *(const short8*)(Vp0 + 64);
  short8 gv1 = *(const short8*)(Vp1 + 64);
  __syncthreads();

  f32x4 yacc[4][4];
#pragma unroll
  for (int qblk = 0; qblk < 4; ++qblk)
#pragma unroll
    for (int dblk = 0; dblk < 4; ++dblk)
      yacc[qblk][dblk] = (f32x4){0.f, 0.f, 0.f, 0.f};
  float sum_l[4] = {0.f, 0.f, 0.f, 0.f};

  // per-wave fragment LDS offsets (element units)
  const int kfo = (wave * 16 + l16) * 72 + quad * 8;   // + ks*32
  int vbo[4];
#pragma unroll
  for (int dblk = 0; dblk < 4; ++dblk) {
    const int d = dblk * 16 + l16;
    const int c = wave * 2 + (quad >> 1);              // t-chunk 0..7
    vbo[dblk] = d * 72 + ((c + (d >> 3)) & 7) * 8 + (quad & 1) * 4;
  }

  for (int kt = 0; kt < 2048; kt += 64) {
    const int cur = (kt >> 6) & 1;
    bf16* KsC = KsB + cur * 4608;
    bf16* VtsC = VtsB + cur * 4608;

    // 1. commit tile kt+64 into the other buffer; prefetch tile kt+128
    if (kt + 64 < 2048) {
      bf16* KsN = KsB + (cur ^ 1) * 4608;
      bf16* VtsN = VtsB + (cur ^ 1) * 4608;
      *(short8*)(KsN + kr * 72 + kc) = gk0;
      *(short8*)(KsN + (kr + 32) * 72 + kc) = gk1;
      *(short8*)(VtsN + voff0) = gv0;
      *(short8*)(VtsN + voff1) = gv1;
      if (kt + 128 < 2048) {
        gk0 = *(const short8*)(Kp0 + (size_t)(kt + 128) * 64);
        gk1 = *(const short8*)(Kp1 + (size_t)(kt + 128) * 64);
        gv0 = *(const short8*)(Vp0 + kt + 128);
        gv1 = *(const short8*)(Vp1 + kt + 128);
      }
    }

    // 2. fragment reads from current buffers
    short8 kf0 = *(const short8*)(KsC + kfo);
    short8 kf1 = *(const short8*)(KsC + kfo + 32);
    s16x4 vb[4];
#pragma unroll
    for (int dblk = 0; dblk < 4; ++dblk)
      vb[dblk] = *(const s16x4*)(VtsC + vbo[dblk]);

    // 3. S^T + softmax -> pa (all in registers)
    s16x4 pa[4];
#pragma unroll
    for (int qblk = 0; qblk < 4; ++qblk) {
      f32x4 a = (f32x4){0.f, 0.f, 0.f, 0.f};
      a = __builtin_amdgcn_mfma_f32_16x16x32_bf16(kf0, qf[qblk][0], a, 0, 0, 0);
      a = __builtin_amdgcn_mfma_f32_16x16x32_bf16(kf1, qf[qblk][1], a, 0, 0, 0);
      float p0 = fast_exp2(a[0]);
      float p1 = fast_exp2(a[1]);
      float p2 = fast_exp2(a[2]);
      float p3 = fast_exp2(a[3]);
      sum_l[qblk] += (p0 + p1) + (p2 + p3);
      uint2 pk;
      pk.x = pack2_bf16(p0, p1);
      pk.y = pack2_bf16(p2, p3);
      pa[qblk] = __builtin_bit_cast(s16x4, pk);
    }

    // 4. Y += P·V over this wave's 16 kv rows (16x16x16 MFMA)
#pragma unroll
    for (int qblk = 0; qblk < 4; ++qblk)
#pragma unroll
      for (int dblk = 0; dblk < 4; ++dblk)
        yacc[qblk][dblk] = MFMA_PV(pa[qblk], vb[dblk], yacc[qblk][dblk]);

    // 5. single barrier: this iter's reads done before next iter's commits
    lds_barrier();
  }

  // ---- epilogue: reduce 4 wave partials (kv quarters) ----
#pragma unroll
  for (int qblk = 0; qblk < 4; ++qblk) {
    sum_l[qblk] += __shfl_xor(sum_l[qblk], 16);
    sum_l[qblk] += __shfl_xor(sum_l[qblk], 32);
  }
  float* red = (float*)pool;                 // 2 x 4096 floats
  float* sred = (float*)(pool + 32768);      // 4 waves x 64 q
  if (lane < 16) {
#pragma unroll
    for (int qblk = 0; qblk < 4; ++qblk)
      sred[wave * 64 + qblk * 16 + l16] = sum_l[qblk];
  }
  if (wave & 1) {                            // waves 1,3 write partials
    float* buf = red + (wave >> 1) * 4096;
#pragma unroll
    for (int qblk = 0; qblk < 4; ++qblk)
#pragma unroll
      for (int dblk = 0; dblk < 4; ++dblk)
        *(f32x4*)&buf[((qblk * 4 + dblk) * 64 + quad * 16 + l16) * 4] =
            yacc[qblk][dblk];
  }
  __syncthreads();
  if (!(wave & 1)) {                         // waves 0,2 accumulate
    float* buf = red + (wave >> 1) * 4096;
#pragma unroll
    for (int qblk = 0; qblk < 4; ++qblk)
#pragma unroll
      for (int dblk = 0; dblk < 4; ++dblk) {
        f32x4 o = *(const f32x4*)&buf[((qblk * 4 + dblk) * 64 + quad * 16 + l16) * 4];
#pragma unroll
        for (int r = 0; r < 4; ++r) yacc[qblk][dblk][r] += o[r];
      }
  }
  __syncthreads();
  if (wave == 2) {                           // wave2 -> buf0
#pragma unroll
    for (int qblk = 0; qblk < 4; ++qblk)
#pragma unroll
      for (int dblk = 0; dblk < 4; ++dblk)
        *(f32x4*)&red[((qblk * 4 + dblk) * 64 + quad * 16 + l16) * 4] =
            yacc[qblk][dblk];
  }
  __syncthreads();
  if (wave == 0) {
    const int b = bh >> 4, h = bh & 15;
    const size_t rowbase = (size_t)b * 2048 + qt * 64;
#pragma unroll
    for (int qblk = 0; qblk < 4; ++qblk) {
      float stot = sred[qblk * 16 + l16] + sred[64 + qblk * 16 + l16] +
                   sred[128 + qblk * 16 + l16] + sred[192 + qblk * 16 + l16];
#pragma unroll
      for (int dblk = 0; dblk < 4; ++dblk) {
        f32x4 o = *(const f32x4*)&red[((qblk * 4 + dblk) * 64 + quad * 16 + l16) * 4];
#pragma unroll
        for (int r = 0; r < 4; ++r) yacc[qblk][dblk][r] += o[r];
      }
#pragma unroll
      for (int r = 0; r < 4; ++r) {
        const float lv = __shfl(stot, quad * 4 + r, 16);
        const float inv = 1.f / lv;
        const int rr = qblk * 16 + quad * 4 + r;
#pragma unroll
        for (int dblk = 0; dblk < 4; ++dblk)
          yg[(rowbase + rr) * 1024 + h * 64 + dblk * 16 + l16] =
              __float2bfloat16(yacc[qblk][dblk][r] * inv);
      }
    }
  }
}

// ---------------- launch ----------------
extern "C" void kernel_launch(void* const* d_in, const int* in_sizes, int n_in,
                              void* d_out, int out_size, void* d_ws, size_t ws_size,
                              hipStream_t stream) {
  const float* x = (const float*)d_in[0];      // [4096, 1024] fp32
  const float* Wqkv = (const float*)d_in[1];   // [1024, 3072] fp32
  const float* bqkv = (const float*)d_in[2];   // [3072] fp32
  const float* Wproj = (const float*)d_in[3];  // [1024, 1024] fp32
  const float* bproj = (const float*)d_in[4];  // [1024] fp32
  float* out = (float*)d_out;                  // [4096, 1024] fp32

  if (ws_size < (size_t)40 * 1024 * 1024) return;

  char* ws = (char*)d_ws;
  bf16* xb    = (bf16*)(ws + 0);             // [4096,1024] = 8 MiB
  bf16* yd    = (bf16*)(ws + 0);             // aliases xb (dead after gemm0)
  bf16* WtQkv = (bf16*)(ws + 8388608);       // [3072,1024] = 6 MiB
  bf16* WtP   = (bf16*)(ws + 14680064);      // [1024,1024] = 2 MiB
  bf16* Qd    = (bf16*)(ws + 16777216);      // [32,2048,64] = 8 MiB (pre-scaled)
  bf16* Kd    = (bf16*)(ws + 25165824);      // 8 MiB
  bf16* Vten  = (bf16*)(ws + 33554432);      // [32,64,2048] = 8 MiB

  prep_k<<<3072, 256, 0, stream>>>(x, xb, Wqkv, WtQkv, Wproj, WtP);
  gemm_bt<0, 128><<<dim3(24, 32), 256, 0, stream>>>(
      xb, WtQkv, bqkv, nullptr, Qd, Kd, Vten, 4096, 3072, 1024);
  attn_kernel<<<dim3(1024), 256, 0, stream>>>(Qd, Kd, Vten, yd);
  gemm_bt<1, 64><<<dim3(8, 64), 256, 0, stream>>>(
      yd, WtP, bproj, out, nullptr, nullptr, nullptr, 4096, 1024, 1024);
}

// Round 3
// 194.767 us; speedup vs baseline: 1.3056x; 1.0379x over previous
//
#include <hip/hip_runtime.h>
#include <hip/hip_bf16.h>
#include <stdint.h>

typedef __hip_bfloat16 bf16;
typedef __attribute__((ext_vector_type(8))) short short8;   // 8 bf16
typedef __attribute__((ext_vector_type(4))) float f32x4;

#define QSCALE 0.18033688011f   // 0.125 * log2(e), folded into Q at gemm0

// ---- 1-instr helpers ----
__device__ __forceinline__ float fast_exp2(float x) {
#if __has_builtin(__builtin_amdgcn_exp2f)
  return __builtin_amdgcn_exp2f(x);
#else
  return exp2f(x);
#endif
}

__device__ __forceinline__ uint32_t pack2_bf16(float a, float b) {
#if __has_builtin(__builtin_amdgcn_cvt_pk_bf16_f32)
  typedef __attribute__((ext_vector_type(2))) __bf16 bf16x2;
  bf16x2 v = __builtin_amdgcn_cvt_pk_bf16_f32(a, b);
  return __builtin_bit_cast(uint32_t, v);
#else
  uint32_t ua = __builtin_bit_cast(uint32_t, a);
  uint32_t ub = __builtin_bit_cast(uint32_t, b);
  ua += 0x7FFF + ((ua >> 16) & 1);   // RNE
  ub += 0x7FFF + ((ub >> 16) & 1);
  return (ua >> 16) | (ub & 0xFFFF0000u);
#endif
}

// async global->LDS, 16B per lane, LDS dest = wave-uniform base + lane*16
__device__ __forceinline__ void gload_lds16(const bf16* g, bf16* l) {
#if __has_builtin(__builtin_amdgcn_global_load_lds)
  __builtin_amdgcn_global_load_lds(
      (const __attribute__((address_space(1))) void*)(uintptr_t)g,
      (__attribute__((address_space(3))) void*)(uint32_t)(uintptr_t)l,
      16, 0, 0);
#else
  int lane = threadIdx.x & 63;
  *(short8*)(l + lane * 8) = *(const short8*)(g + lane * 8);
#endif
}

// LDS-only barrier (no vmcnt drain): keeps global prefetch loads in flight.
__device__ __forceinline__ void lds_barrier() {
  asm volatile("s_waitcnt lgkmcnt(0)\n\ts_barrier" ::: "memory");
}

// ---- fp32->bf16 transpose tile body (64x64) ----
__device__ __forceinline__ void transpose_tile(const float* __restrict__ in,
                                               bf16* __restrict__ out,
                                               int R, int C, int bx, int by,
                                               bf16 (*t)[72]) {
  const int r0 = by * 64, c0 = bx * 64;
  const int rr = threadIdx.x >> 3, cc = (threadIdx.x & 7) * 8;
#pragma unroll
  for (int rep = 0; rep < 2; ++rep) {
    int y = rr + rep * 32;
    const float* p = in + (size_t)(r0 + y) * C + c0 + cc;
    f32x4 v0 = *(const f32x4*)p;
    f32x4 v1 = *(const f32x4*)(p + 4);
#pragma unroll
    for (int j = 0; j < 4; ++j) {
      t[cc + j][y] = __float2bfloat16(v0[j]);
      t[cc + 4 + j][y] = __float2bfloat16(v1[j]);
    }
  }
  __syncthreads();
#pragma unroll
  for (int rep = 0; rep < 2; ++rep) {
    int y = rr + rep * 32;
    short8 v = *(const short8*)&t[y][cc];
    *(short8*)(out + (size_t)(c0 + y) * R + r0 + cc) = v;
  }
}

// ---- fused prep: x->bf16 (blocks 0..2047), Wqkv^T (2048..2815),
//      Wproj^T (2816..3071) ----
__global__ __launch_bounds__(256)
void prep_k(const float* __restrict__ x, bf16* __restrict__ xb,
            const float* __restrict__ Wqkv, bf16* __restrict__ WtQkv,
            const float* __restrict__ Wproj, bf16* __restrict__ WtP) {
  __shared__ __align__(16) bf16 t[64][72];
  const int bid = blockIdx.x;
  if (bid < 2048) {
    int i = (bid * 256 + threadIdx.x) * 8;
    f32x4 v0 = *(const f32x4*)(x + i);
    f32x4 v1 = *(const f32x4*)(x + i + 4);
    short8 r;
    bf16* rb = (bf16*)&r;
#pragma unroll
    for (int j = 0; j < 4; ++j) {
      rb[j] = __float2bfloat16(v0[j]);
      rb[4 + j] = __float2bfloat16(v1[j]);
    }
    *(short8*)(xb + i) = r;
  } else if (bid < 2048 + 768) {
    int b = bid - 2048;
    transpose_tile(Wqkv, WtQkv, 1024, 3072, b % 48, b / 48, t);
  } else {
    int b = bid - 2816;
    transpose_tile(Wproj, WtP, 1024, 1024, b % 16, b / 16, t);
  }
}

// ---------------- GEMM: C[m][n] = A[m,:]·Bt[n,:] + bias[n] -------------------
// MODE 0 (TM=128): LDS-transposed coalesced epilogue -> Q (xQSCALE) / K as
//                  [bh][t][64], V^T as [bh][64][t]. All 16B/lane stores.
// MODE 1 (TM=64):  fp32 out row-major [M,Nn].
template <int MODE, int TM>
__global__ __launch_bounds__(256, 2)
void gemm_bt(const bf16* __restrict__ A, const bf16* __restrict__ Bt,
             const float* __restrict__ bias, float* __restrict__ outp,
             bf16* __restrict__ Qd, bf16* __restrict__ Kd, bf16* __restrict__ Vt,
             int M, int Nn, int K) {
  constexpr int MI = TM / 32;
  // staging (TM*32 + 4096 el) and MODE-0 epilogue (<=9216 el) share this pool
  __shared__ __align__(16) bf16 smem[(TM == 128) ? 9216 : 6144];
  bf16* As = smem;
  bf16* Bs = smem + TM * 32;

  const int tid = threadIdx.x;
  const int wave = tid >> 6, lane = tid & 63;
  const int quad = lane >> 4, l16 = lane & 15;
  const int mw = (wave >> 1) * (TM / 2), nw = (wave & 1) * 64;
  const int m_blk = blockIdx.y * TM, n_blk = blockIdx.x * 128;

  f32x4 acc[MI][4];
#pragma unroll
  for (int i = 0; i < MI; ++i)
#pragma unroll
    for (int j = 0; j < 4; ++j) acc[i][j] = (f32x4){0.f, 0.f, 0.f, 0.f};

  const int rowA = lane >> 2, colA = (lane & 3) * 8;
  const int chunkB = wave * 2;
  const bf16* gB = Bt + (size_t)(n_blk + chunkB * 16 + rowA) * K + colA;
  bf16* lB0 = &Bs[chunkB * 16 * 32];
  bf16* lB1 = &Bs[(chunkB + 1) * 16 * 32];

  const int chunkA = (TM == 128) ? wave * 2 : wave;
  const bf16* gA = A + (size_t)(m_blk + chunkA * 16 + rowA) * K + colA;
  bf16* lA0 = &As[chunkA * 16 * 32];
  bf16* lA1 = &As[(chunkA + 1) * 16 * 32];  // unused for TM=64

  for (int kt = 0; kt < K; kt += 32) {
    gload_lds16(gA, lA0);
    if (TM == 128) gload_lds16(gA + 16 * K, lA1);
    gload_lds16(gB, lB0);
    gload_lds16(gB + 16 * K, lB1);
    gA += 32; gB += 32;
    __syncthreads();
    short8 af[MI], bfv[4];
#pragma unroll
    for (int i = 0; i < MI; ++i)
      af[i] = *(const short8*)&As[(mw + i * 16 + l16) * 32 + quad * 8];
#pragma unroll
    for (int j = 0; j < 4; ++j)
      bfv[j] = *(const short8*)&Bs[(nw + j * 16 + l16) * 32 + quad * 8];
#pragma unroll
    for (int i = 0; i < MI; ++i)
#pragma unroll
      for (int j = 0; j < 4; ++j)
        acc[i][j] = __builtin_amdgcn_mfma_f32_16x16x32_bf16(af[i], bfv[j],
                                                            acc[i][j], 0, 0, 0);
    __syncthreads();
  }

  if (MODE == 0) {
    // per-j bias for this wave's columns
    float bval[4];
#pragma unroll
    for (int j = 0; j < 4; ++j) bval[j] = bias[n_blk + nw + j * 16 + l16];

    const int part = n_blk >> 10;          // 0:q 1:k 2:v (block-uniform)
    const int b = m_blk >> 11;
    const int tloc = m_blk & 2047;
    const int h0 = (n_blk & 1023) >> 6;

#pragma unroll
    for (int p = 0; p < 2; ++p) {          // feature halves (64 cols = 1 head)
      __syncthreads();
      if ((nw >> 6) == p) {
        if (part == 2) {
          // V half-tile as [64 d][136 t], 8B-packed writes (r -> t contiguous)
#pragma unroll
          for (int i = 0; i < MI; ++i)
#pragma unroll
            for (int j = 0; j < 4; ++j) {
              const int dh = j * 16 + l16;
              const int t0 = mw + i * 16 + quad * 4;
              uint2 pk;
              pk.x = pack2_bf16(acc[i][j][0] + bval[j], acc[i][j][1] + bval[j]);
              pk.y = pack2_bf16(acc[i][j][2] + bval[j], acc[i][j][3] + bval[j]);
              *(uint2*)&smem[dh * 136 + t0] = pk;
            }
        } else {
          // Q/K half-tile as [128 t][72 d] (stride-72: conflict-free writes)
          const float sc = (part == 0) ? QSCALE : 1.0f;
#pragma unroll
          for (int i = 0; i < MI; ++i)
#pragma unroll
            for (int j = 0; j < 4; ++j) {
              const int d = j * 16 + l16;
              const int t0 = mw + i * 16 + quad * 4;
#pragma unroll
              for (int r = 0; r < 4; ++r)
                smem[(t0 + r) * 72 + d] =
                    __float2bfloat16((acc[i][j][r] + bval[j]) * sc);
            }
        }
      }
      __syncthreads();
      const size_t bh = (size_t)(b * 16 + h0 + p);
      if (part == 2) {
#pragma unroll
        for (int it = 0; it < 4; ++it) {
          const int dl = (tid >> 4) + it * 16;
          const int t8 = (tid & 15) * 8;
          short8 v = *(const short8*)&smem[dl * 136 + t8];
          *(short8*)&Vt[(bh * 64 + dl) * 2048 + tloc + t8] = v;
        }
      } else {
        bf16* dst = (part == 0) ? Qd : Kd;
#pragma unroll
        for (int it = 0; it < 4; ++it) {
          const int row = (tid >> 3) + it * 32;
          const int col8 = (tid & 7) * 8;
          short8 v = *(const short8*)&smem[row * 72 + col8];
          *(short8*)&dst[(bh * 2048 + tloc + row) * 64 + col8] = v;
        }
      }
    }
  } else {
#pragma unroll
    for (int j = 0; j < 4; ++j) {
      const int ncol = n_blk + nw + j * 16 + l16;
      const float bval = bias[ncol];
#pragma unroll
      for (int i = 0; i < MI; ++i) {
        const int mrow0 = m_blk + mw + i * 16 + quad * 4;
#pragma unroll
        for (int r = 0; r < 4; ++r)
          outp[(size_t)(mrow0 + r) * Nn + ncol] = acc[i][j][r] + bval;
      }
    }
  }
}

// ---------------- flash attention: Qtile=64, KVtile=64, quadrant split -------
// Wave (qh,kvh) owns q-half x kv-half. S^T = K·Q^T per 16-kv subtile:
// lane (quad,l16) holds S[q=l16][kv=quad*4+r]. Concatenating the two 16-kv
// subtiles per lane gives the 16x16x32 A-fragment under k-slot permutation
// pi(quad*8+e) = {quad*4+e (e<4), 16+quad*4+e-4 (e>=4)}. Feeding V with the
// SAME pi (two b64 reads from V^T LDS) keeps the MFMA contraction exact, so
// P = exp2(S) stays entirely in registers: no P LDS round-trip, no transpose,
// PV at full K=32 rate. K/V double-buffered; ONE lds_barrier per iteration.
__global__ __launch_bounds__(256, 4)
void attn_kernel(const bf16* __restrict__ Qg, const bf16* __restrict__ Kg,
                 const bf16* __restrict__ Vt, bf16* __restrict__ yg) {
  // [0,18432): Ks[2][64][72]; [18432,36864): Vts[2][64*72].
  // Epilogue reuse: red = 16 KiB partials at 0; sred = 256 B at 16384.
  __shared__ __align__(16) char pool[36864];
  bf16* KsB = (bf16*)pool;
  bf16* VtsB = (bf16*)(pool + 18432);

  const int tid = threadIdx.x;
  const int wave = tid >> 6, lane = tid & 63;
  const int quad = lane >> 4, l16 = lane & 15;
  const int qh = wave & 1, kvh = wave >> 1;

  const int bx = blockIdx.x;
  const int qt = bx & 31;                // 32 q-tiles of 64
  const int bh = bx >> 5;                // b*16 + h

  const bf16* Qb = Qg + ((size_t)bh * 2048 + qt * 64) * 64;
  const bf16* Kb = Kg + (size_t)bh * 2048 * 64;
  const bf16* Vtb = Vt + (size_t)bh * 64 * 2048;

  // Q fragments (pre-scaled by QSCALE at gemm0)
  short8 qf[2][2];
#pragma unroll
  for (int qblk = 0; qblk < 2; ++qblk)
#pragma unroll
    for (int ks = 0; ks < 2; ++ks)
      qf[qblk][ks] = *(const short8*)(
          Qb + (size_t)(qh * 32 + qblk * 16 + l16) * 64 + ks * 32 + quad * 8);

  // staging addressing (block-cooperative, coalesced global reads)
  const int kr = tid >> 3, kc = (tid & 7) * 8;
  const int vdd = tid & 63, vo = tid >> 6;
  const int voff0 = vdd * 72 + (((vo) + (vdd >> 3)) & 7) * 8;
  const int voff1 = vdd * 72 + (((vo + 4) + (vdd >> 3)) & 7) * 8;
  const bf16* Kp0 = Kb + (size_t)kr * 64 + kc;
  const bf16* Kp1 = Kb + (size_t)(kr + 32) * 64 + kc;
  const bf16* Vp0 = Vtb + (size_t)vdd * 2048 + vo * 8;
  const bf16* Vp1 = Vtb + (size_t)vdd * 2048 + (vo + 4) * 8;

  // preamble: tile0 -> buf0; tile1 -> regs
  {
    short8 a = *(const short8*)Kp0;
    short8 b = *(const short8*)Kp1;
    short8 c = *(const short8*)Vp0;
    short8 d = *(const short8*)Vp1;
    *(short8*)(KsB + kr * 72 + kc) = a;
    *(short8*)(KsB + (kr + 32) * 72 + kc) = b;
    *(short8*)(VtsB + voff0) = c;
    *(short8*)(VtsB + voff1) = d;
  }
  short8 gk0 = *(const short8*)(Kp0 + (size_t)64 * 64);
  short8 gk1 = *(const short8*)(Kp1 + (size_t)64 * 64);
  short8 gv0 = *(const short8*)(Vp0 + 64);
  short8 gv1 = *(const short8*)(Vp1 + 64);
  __syncthreads();

  f32x4 yacc[2][4];
#pragma unroll
  for (int qblk = 0; qblk < 2; ++qblk)
#pragma unroll
    for (int dblk = 0; dblk < 4; ++dblk)
      yacc[qblk][dblk] = (f32x4){0.f, 0.f, 0.f, 0.f};
  float sum_l[2] = {0.f, 0.f};

  // per-wave fragment LDS offsets (element units)
  const int kfo = (kvh * 32 + l16) * 72 + quad * 8;    // + kvblk*16*72 + ks*32
  int vbo[4][2];                                        // b64 reads, pi-permuted
#pragma unroll
  for (int dblk = 0; dblk < 4; ++dblk) {
    const int d = dblk * 16 + l16;
#pragma unroll
    for (int kvblk = 0; kvblk < 2; ++kvblk) {
      const int c = kvh * 4 + kvblk * 2 + (quad >> 1); // t-chunk 0..7
      vbo[dblk][kvblk] = d * 72 + ((c + (d >> 3)) & 7) * 8 + (quad & 1) * 4;
    }
  }

  for (int kt = 0; kt < 2048; kt += 64) {
    const int cur = (kt >> 6) & 1;
    bf16* KsC = KsB + cur * 4608;
    bf16* VtsC = VtsB + cur * 4608;

    // 1. commit tile kt+64 into the other buffer; prefetch tile kt+128
    if (kt + 64 < 2048) {
      bf16* KsN = KsB + (cur ^ 1) * 4608;
      bf16* VtsN = VtsB + (cur ^ 1) * 4608;
      *(short8*)(KsN + kr * 72 + kc) = gk0;
      *(short8*)(KsN + (kr + 32) * 72 + kc) = gk1;
      *(short8*)(VtsN + voff0) = gv0;
      *(short8*)(VtsN + voff1) = gv1;
      if (kt + 128 < 2048) {
        gk0 = *(const short8*)(Kp0 + (size_t)(kt + 128) * 64);
        gk1 = *(const short8*)(Kp1 + (size_t)(kt + 128) * 64);
        gv0 = *(const short8*)(Vp0 + kt + 128);
        gv1 = *(const short8*)(Vp1 + kt + 128);
      }
    }

    // 2. K fragments for this wave's kv-half
    short8 kf[2][2];
#pragma unroll
    for (int kvblk = 0; kvblk < 2; ++kvblk)
#pragma unroll
      for (int ks = 0; ks < 2; ++ks)
        kf[kvblk][ks] =
            *(const short8*)(KsC + kfo + kvblk * 16 * 72 + ks * 32);

    // 3. S^T + softmax -> pa8 (P stays in registers, pi-ordered over 32 kv)
    short8 pa8[2];
#pragma unroll
    for (int qblk = 0; qblk < 2; ++qblk) {
      f32x4 s0 = (f32x4){0.f, 0.f, 0.f, 0.f};
      f32x4 s1 = (f32x4){0.f, 0.f, 0.f, 0.f};
      s0 = __builtin_amdgcn_mfma_f32_16x16x32_bf16(kf[0][0], qf[qblk][0], s0, 0, 0, 0);
      s0 = __builtin_amdgcn_mfma_f32_16x16x32_bf16(kf[0][1], qf[qblk][1], s0, 0, 0, 0);
      s1 = __builtin_amdgcn_mfma_f32_16x16x32_bf16(kf[1][0], qf[qblk][0], s1, 0, 0, 0);
      s1 = __builtin_amdgcn_mfma_f32_16x16x32_bf16(kf[1][1], qf[qblk][1], s1, 0, 0, 0);
      float p0 = fast_exp2(s0[0]), p1 = fast_exp2(s0[1]);
      float p2 = fast_exp2(s0[2]), p3 = fast_exp2(s0[3]);
      float p4 = fast_exp2(s1[0]), p5 = fast_exp2(s1[1]);
      float p6 = fast_exp2(s1[2]), p7 = fast_exp2(s1[3]);
      sum_l[qblk] += ((p0 + p1) + (p2 + p3)) + ((p4 + p5) + (p6 + p7));
      uint4 u;
      u.x = pack2_bf16(p0, p1);
      u.y = pack2_bf16(p2, p3);
      u.z = pack2_bf16(p4, p5);
      u.w = pack2_bf16(p6, p7);
      pa8[qblk] = __builtin_bit_cast(short8, u);
    }

    // 4. Y += P·V, K=32 MFMA with pi-permuted V fragments (two b64 each)
#pragma unroll
    for (int dblk = 0; dblk < 4; ++dblk) {
      uint2 lo = *(const uint2*)(VtsC + vbo[dblk][0]);
      uint2 hi = *(const uint2*)(VtsC + vbo[dblk][1]);
      uint4 u;
      u.x = lo.x; u.y = lo.y; u.z = hi.x; u.w = hi.y;
      short8 vb8 = __builtin_bit_cast(short8, u);
      yacc[0][dblk] = __builtin_amdgcn_mfma_f32_16x16x32_bf16(
          pa8[0], vb8, yacc[0][dblk], 0, 0, 0);
      yacc[1][dblk] = __builtin_amdgcn_mfma_f32_16x16x32_bf16(
          pa8[1], vb8, yacc[1][dblk], 0, 0, 0);
    }

    // 5. single barrier: this iter's reads done before next iter's commits
    lds_barrier();
  }

  // ---- reductions: quads within wave, then kv-halves across waves ----
#pragma unroll
  for (int qblk = 0; qblk < 2; ++qblk) {
    sum_l[qblk] += __shfl_xor(sum_l[qblk], 16);
    sum_l[qblk] += __shfl_xor(sum_l[qblk], 32);
  }
  __syncthreads();   // all waves done with K/V LDS before scratch overwrites
  float* red = (float*)pool;                 // 16384 B Y-partials
  float* sred = (float*)(pool + 16384);      // 256 B sums
  if (kvh == 1) {
#pragma unroll
    for (int qblk = 0; qblk < 2; ++qblk) {
#pragma unroll
      for (int dblk = 0; dblk < 4; ++dblk) {
        const int f = (qh * 2 + qblk) * 4 + dblk;
        *(f32x4*)&red[(f * 64 + quad * 16 + l16) * 4] = yacc[qblk][dblk];
      }
      if (quad == 0) sred[(qh * 2 + qblk) * 16 + l16] = sum_l[qblk];
    }
  }
  __syncthreads();
  if (kvh == 0) {
    const int b = bh >> 4, h = bh & 15;
    const size_t rowbase = (size_t)b * 2048 + qt * 64;
#pragma unroll
    for (int qblk = 0; qblk < 2; ++qblk) {
      sum_l[qblk] += sred[(qh * 2 + qblk) * 16 + l16];
#pragma unroll
      for (int dblk = 0; dblk < 4; ++dblk) {
        const int f = (qh * 2 + qblk) * 4 + dblk;
        f32x4 o = *(const f32x4*)&red[(f * 64 + quad * 16 + l16) * 4];
#pragma unroll
        for (int r = 0; r < 4; ++r) yacc[qblk][dblk][r] += o[r];
      }
#pragma unroll
      for (int r = 0; r < 4; ++r) {
        const float lv = __shfl(sum_l[qblk], quad * 4 + r, 16);
        const float inv = 1.f / lv;
        const int rr = qh * 32 + qblk * 16 + quad * 4 + r;
#pragma unroll
        for (int dblk = 0; dblk < 4; ++dblk)
          yg[(rowbase + rr) * 1024 + h * 64 + dblk * 16 + l16] =
              __float2bfloat16(yacc[qblk][dblk][r] * inv);
      }
    }
  }
}

// ---------------- launch ----------------
extern "C" void kernel_launch(void* const* d_in, const int* in_sizes, int n_in,
                              void* d_out, int out_size, void* d_ws, size_t ws_size,
                              hipStream_t stream) {
  const float* x = (const float*)d_in[0];      // [4096, 1024] fp32
  const float* Wqkv = (const float*)d_in[1];   // [1024, 3072] fp32
  const float* bqkv = (const float*)d_in[2];   // [3072] fp32
  const float* Wproj = (const float*)d_in[3];  // [1024, 1024] fp32
  const float* bproj = (const float*)d_in[4];  // [1024] fp32
  float* out = (float*)d_out;                  // [4096, 1024] fp32

  if (ws_size < (size_t)40 * 1024 * 1024) return;

  char* ws = (char*)d_ws;
  bf16* xb    = (bf16*)(ws + 0);             // [4096,1024] = 8 MiB
  bf16* yd    = (bf16*)(ws + 0);             // aliases xb (dead after gemm0)
  bf16* WtQkv = (bf16*)(ws + 8388608);       // [3072,1024] = 6 MiB
  bf16* WtP   = (bf16*)(ws + 14680064);      // [1024,1024] = 2 MiB
  bf16* Qd    = (bf16*)(ws + 16777216);      // [32,2048,64] = 8 MiB (pre-scaled)
  bf16* Kd    = (bf16*)(ws + 25165824);      // 8 MiB
  bf16* Vten  = (bf16*)(ws + 33554432);      // [32,64,2048] = 8 MiB

  prep_k<<<3072, 256, 0, stream>>>(x, xb, Wqkv, WtQkv, Wproj, WtP);
  gemm_bt<0, 128><<<dim3(24, 32), 256, 0, stream>>>(
      xb, WtQkv, bqkv, nullptr, Qd, Kd, Vten, 4096, 3072, 1024);
  attn_kernel<<<dim3(1024), 256, 0, stream>>>(Qd, Kd, Vten, yd);
  gemm_bt<1, 64><<<dim3(8, 64), 256, 0, stream>>>(
      yd, WtP, bproj, out, nullptr, nullptr, nullptr, 4096, 1024, 1024);
}